// Round 1
// baseline (17259.480 us; speedup 1.0000x reference)
//
#include <hip/hip_runtime.h>

#define HD 300
#define BD 64
#define VD 100000
#define LD 64

__device__ __forceinline__ float sigm(float x) { return 1.0f / (1.0f + expf(-x)); }

// ---------------------------------------------------------------------------
// GRU step: h_out = GRU(x, h_in). Covers encoder (x = emb[ids], no relu) and
// decoder (x = x_buf rows, already relu'd). Block = 2 batch rows x 100 outputs.
// Weight rows: per-lane float4 streams (L2-hot, 2.16 MB total).
// x/h reads: wave-uniform addresses -> scalar loads (s_load_dwordx4).
// ---------------------------------------------------------------------------
__global__ __launch_bounds__(128) void k_gru(
    const float* __restrict__ xbase, const int* __restrict__ ids,
    const float* __restrict__ emb,
    const float* __restrict__ W_ih, const float* __restrict__ W_hh,
    const float* __restrict__ b_ih, const float* __restrict__ b_hh,
    const float* __restrict__ h_in, float* __restrict__ h_out)
{
  const int bg = blockIdx.x;            // 0..31 -> batch rows 2*bg, 2*bg+1
  const int ic = blockIdx.y;            // 0..2  -> output chunk
  const int i  = ic * 100 + threadIdx.x;
  if (threadIdx.x >= 100) return;
  const int b0 = bg * 2;

  const float* xr0;
  const float* xr1;
  if (ids) {                            // encoder: x = emb[input[t][b]]
    xr0 = emb + (size_t)ids[b0] * HD;
    xr1 = emb + (size_t)ids[b0 + 1] * HD;
  } else {                              // decoder: x = x_buf[b] (relu'd)
    xr0 = xbase + (size_t)b0 * HD;
    xr1 = xbase + (size_t)(b0 + 1) * HD;
  }
  const float* hr0 = h_in + (size_t)b0 * HD;
  const float* hr1 = hr0 + HD;

  const float* wr = W_ih + (size_t)i * HD;        // rows i, i+300, i+600
  const float* wz = wr + (size_t)HD * HD;
  const float* wn = wz + (size_t)HD * HD;
  const float* ur = W_hh + (size_t)i * HD;
  const float* uz = ur + (size_t)HD * HD;
  const float* un = uz + (size_t)HD * HD;

  float air0 = 0.f, aiz0 = 0.f, ain0 = 0.f, ahr0 = 0.f, ahz0 = 0.f, ahn0 = 0.f;
  float air1 = 0.f, aiz1 = 0.f, ain1 = 0.f, ahr1 = 0.f, ahz1 = 0.f, ahn1 = 0.f;

  for (int k = 0; k < HD; k += 4) {
    const float4 a = *(const float4*)(wr + k);
    const float4 bq = *(const float4*)(wz + k);
    const float4 c = *(const float4*)(wn + k);
    const float4 d = *(const float4*)(ur + k);
    const float4 e = *(const float4*)(uz + k);
    const float4 f = *(const float4*)(un + k);
    const float4 x0 = *(const float4*)(xr0 + k);   // uniform -> s_load
    const float4 x1 = *(const float4*)(xr1 + k);
    const float4 h0 = *(const float4*)(hr0 + k);
    const float4 h1 = *(const float4*)(hr1 + k);

    air0 += a.x * x0.x + a.y * x0.y + a.z * x0.z + a.w * x0.w;
    aiz0 += bq.x * x0.x + bq.y * x0.y + bq.z * x0.z + bq.w * x0.w;
    ain0 += c.x * x0.x + c.y * x0.y + c.z * x0.z + c.w * x0.w;
    ahr0 += d.x * h0.x + d.y * h0.y + d.z * h0.z + d.w * h0.w;
    ahz0 += e.x * h0.x + e.y * h0.y + e.z * h0.z + e.w * h0.w;
    ahn0 += f.x * h0.x + f.y * h0.y + f.z * h0.z + f.w * h0.w;

    air1 += a.x * x1.x + a.y * x1.y + a.z * x1.z + a.w * x1.w;
    aiz1 += bq.x * x1.x + bq.y * x1.y + bq.z * x1.z + bq.w * x1.w;
    ain1 += c.x * x1.x + c.y * x1.y + c.z * x1.z + c.w * x1.w;
    ahr1 += d.x * h1.x + d.y * h1.y + d.z * h1.z + d.w * h1.w;
    ahz1 += e.x * h1.x + e.y * h1.y + e.z * h1.z + e.w * h1.w;
    ahn1 += f.x * h1.x + f.y * h1.y + f.z * h1.z + f.w * h1.w;
  }

  const float br = b_ih[i], bz = b_ih[i + HD], bn = b_ih[i + 2 * HD];
  const float cr = b_hh[i], cz = b_hh[i + HD], cn = b_hh[i + 2 * HD];

  {
    const float r = sigm((air0 + br) + (ahr0 + cr));
    const float z = sigm((aiz0 + bz) + (ahz0 + cz));
    const float n = tanhf((ain0 + bn) + r * (ahn0 + cn));
    h_out[(size_t)b0 * HD + i] = (1.f - z) * n + z * hr0[i];
  }
  {
    const float r = sigm((air1 + br) + (ahr1 + cr));
    const float z = sigm((aiz1 + bz) + (ahz1 + cz));
    const float n = tanhf((ain1 + bn) + r * (ahn1 + cn));
    h_out[(size_t)(b0 + 1) * HD + i] = (1.f - z) * n + z * hr1[i];
  }
}

// ---------------------------------------------------------------------------
// Output projection: logits[b][v] = dot(h[b], out_W[v]) + out_b[v].
// Thread = 1 vocab column with acc[32] (half the batch); 782 blocks x 256 thr
// -> ~3 waves/SIMD. Inner iter: 1 float4 weight load + 32 scalar-load rows of
// h + 128 v_fma (scalar operand) -> near fp32 VALU peak.
// ---------------------------------------------------------------------------
__global__ __launch_bounds__(256) void k_proj(
    const float* __restrict__ h,      // [B][H]
    const float* __restrict__ outW,   // [V][H]
    const float* __restrict__ outb,   // [V]
    float* __restrict__ logits)       // [B][V]
{
  const int vc = blockIdx.x >> 1;
  const int bg = blockIdx.x & 1;      // batch half
  const int v  = vc * 256 + threadIdx.x;
  if (v >= VD) return;
  const int b0 = bg * 32;

  const float* wrow = outW + (size_t)v * HD;

  float acc[32];
#pragma unroll
  for (int t = 0; t < 32; t++) acc[t] = 0.f;

  for (int k = 0; k < HD; k += 4) {
    const float4 w = *(const float4*)(wrow + k);
#pragma unroll
    for (int bb = 0; bb < 32; bb++) {
      const float4 hv = *(const float4*)(h + (size_t)(b0 + bb) * HD + k);  // uniform -> s_load
      acc[bb] += w.x * hv.x + w.y * hv.y + w.z * hv.z + w.w * hv.w;
    }
  }

  const float ob = outb[v];
#pragma unroll
  for (int bb = 0; bb < 32; bb++) {
    logits[(size_t)(b0 + bb) * VD + v] = acc[bb] + ob;
  }
}

// ---------------------------------------------------------------------------
// Argmax over logits row + write out[s][b] + pre-gather relu(emb[id]) into
// x_buf for the next decoder step. Packed u64 key: (orderable_f32, ~idx) so
// max() gives first-index tie-break like jnp.argmax.
// ---------------------------------------------------------------------------
__device__ __forceinline__ unsigned long long shflxor_u64(unsigned long long v, int m) {
  int lo = (int)(unsigned)v;
  int hi = (int)(unsigned)(v >> 32);
  lo = __shfl_xor(lo, m, 64);
  hi = __shfl_xor(hi, m, 64);
  return ((unsigned long long)(unsigned)hi << 32) | (unsigned)lo;
}

__global__ __launch_bounds__(1024) void k_argmax(
    const float* __restrict__ logits,  // [B][V]
    const float* __restrict__ emb,
    float* __restrict__ out_row,       // out + s*B
    float* __restrict__ x_buf)         // [B][H], relu'd next x
{
  const int b = blockIdx.x;
  const float* row = logits + (size_t)b * VD;

  unsigned long long best = 0ull;
  for (int v = threadIdx.x; v < VD; v += 1024) {
    const float fv = row[v];
    unsigned u = __float_as_uint(fv);
    u = (u & 0x80000000u) ? ~u : (u | 0x80000000u);
    const unsigned long long key =
        ((unsigned long long)u << 32) | (unsigned long long)(0xFFFFFFFFu - (unsigned)v);
    if (key > best) best = key;
  }

#pragma unroll
  for (int m = 32; m >= 1; m >>= 1) {
    const unsigned long long o = shflxor_u64(best, m);
    if (o > best) best = o;
  }

  __shared__ unsigned long long smax[16];
  __shared__ int sid;
  const int wv = threadIdx.x >> 6;
  const int ln = threadIdx.x & 63;
  if (ln == 0) smax[wv] = best;
  __syncthreads();
  if (threadIdx.x == 0) {
    unsigned long long m = smax[0];
#pragma unroll
    for (int i = 1; i < 16; i++)
      if (smax[i] > m) m = smax[i];
    const int id = (int)(0xFFFFFFFFu - (unsigned)(m & 0xFFFFFFFFull));
    out_row[b] = (float)id;
    sid = id;
  }
  __syncthreads();

  const int id = sid;
  for (int i = threadIdx.x; i < HD; i += 1024) {
    x_buf[(size_t)b * HD + i] = fmaxf(emb[(size_t)id * HD + i], 0.f);
  }
}

// ---------------------------------------------------------------------------
// Init: h0 = 0, x_buf = relu(emb[0]) (decoder init_ids are zeros).
// ---------------------------------------------------------------------------
__global__ __launch_bounds__(320) void k_init(
    float* __restrict__ h0, const float* __restrict__ emb, float* __restrict__ x_buf)
{
  const int b = blockIdx.x;
  const int i = threadIdx.x;
  if (i < HD) {
    h0[(size_t)b * HD + i] = 0.f;
    x_buf[(size_t)b * HD + i] = fmaxf(emb[i], 0.f);
  }
}

// ---------------------------------------------------------------------------
extern "C" void kernel_launch(void* const* d_in, const int* in_sizes, int n_in,
                              void* d_out, int out_size, void* d_ws, size_t ws_size,
                              hipStream_t stream) {
  const int*   input  = (const int*)d_in[0];    // [L][B] int32
  const float* emb    = (const float*)d_in[1];  // [V][H]
  const float* eWih   = (const float*)d_in[2];
  const float* eWhh   = (const float*)d_in[3];
  const float* eBih   = (const float*)d_in[4];
  const float* eBhh   = (const float*)d_in[5];
  const float* dWih   = (const float*)d_in[6];
  const float* dWhh   = (const float*)d_in[7];
  const float* dBih   = (const float*)d_in[8];
  const float* dBhh   = (const float*)d_in[9];
  const float* outW   = (const float*)d_in[10]; // [V][H]
  const float* outb   = (const float*)d_in[11]; // [V]
  float* out = (float*)d_out;                   // [L][B] float token ids

  float* ws = (float*)d_ws;
  float* h0buf = ws;                    // 64*300
  float* h1buf = ws + 19200;            // 64*300
  float* x_buf = ws + 38400;            // 64*300
  float* lg    = ws + 57600;            // 64*100000 = 6.4e6 floats (~25.6 MB)

  k_init<<<BD, 320, 0, stream>>>(h0buf, emb, x_buf);

  // ---- encoder: 64 sequential GRU steps over token embeddings ----
  for (int t = 0; t < LD; t++) {
    float* hin  = (t & 1) ? h1buf : h0buf;
    float* hout = (t & 1) ? h0buf : h1buf;
    k_gru<<<dim3(32, 3), 128, 0, stream>>>(nullptr, input + t * BD, emb,
                                           eWih, eWhh, eBih, eBhh, hin, hout);
  }
  // after t=63 (odd): enc_h lives in h0buf

  // ---- decoder: 64 sequential steps of GRU + projection + argmax ----
  for (int s = 0; s < LD; s++) {
    float* hin  = (s & 1) ? h1buf : h0buf;
    float* hout = (s & 1) ? h0buf : h1buf;
    k_gru<<<dim3(32, 3), 128, 0, stream>>>(x_buf, nullptr, emb,
                                           dWih, dWhh, dBih, dBhh, hin, hout);
    k_proj<<<782, 256, 0, stream>>>(hout, outW, outb, lg);
    k_argmax<<<BD, 1024, 0, stream>>>(lg, emb, out + s * BD, x_buf);
  }
}